// Round 4
// baseline (193.269 us; speedup 1.0000x reference)
//
#include <hip/hip_runtime.h>
#include <hip/hip_bf16.h>

#define BSZ 8192
#define BTZ 8192
#define DD 64
#define NC 10
#define SHIFT2 20.0f   // log2-domain shift
#define LN2 0.69314718055994531f
#define LOG2E 1.44269504088896341f
#define NEG_BIG -1.0e30f

typedef __attribute__((ext_vector_type(8))) short bf16x8;
typedef __attribute__((ext_vector_type(4))) float f32x4;

#if defined(__has_builtin)
#if __has_builtin(__builtin_amdgcn_exp2f)
#define EXP2(x) __builtin_amdgcn_exp2f(x)
#else
#define EXP2(x) exp2f(x)
#endif
#else
#define EXP2(x) exp2f(x)
#endif

#define MFMA16(A, B, C) __builtin_amdgcn_mfma_f32_16x16x32_bf16(A, B, C, 0, 0, 0)

__device__ __forceinline__ unsigned short f2bf_rne(float f) {
    unsigned int u = __float_as_uint(f);
    u += 0x7FFFu + ((u >> 16) & 1u);
    return (unsigned short)(u >> 16);
}

// 10-way register accumulate; c wave-uniform scalar (from readlane) -> s_cbranch chain.
#define ACC10(A, c, v) {                      \
    if      ((c) == 0) A[0] += (v);           \
    else if ((c) == 1) A[1] += (v);           \
    else if ((c) == 2) A[2] += (v);           \
    else if ((c) == 3) A[3] += (v);           \
    else if ((c) == 4) A[4] += (v);           \
    else if ((c) == 5) A[5] += (v);           \
    else if ((c) == 6) A[6] += (v);           \
    else if ((c) == 7) A[7] += (v);           \
    else if ((c) == 8) A[8] += (v);           \
    else if ((c) == 9) A[9] += (v); }         // c==255 (dead) falls through

// 8-row load group (unconditional, independent -> deep in flight) and accumulate group.
#define LD8(buf, g) { _Pragma("unroll")       \
    for (int kk = 0; kk < 8; ++kk) buf[kk] = rowp[(size_t)((((g) * 8) + kk) * 64)]; }
#define AC8(buf, g, A) { _Pragma("unroll")    \
    for (int kk = 0; kk < 8; ++kk) {          \
        int c_ = __builtin_amdgcn_readlane(myc, (g) * 8 + kk);  \
        ACC10(A, c_, buf[kk]); } }

// Kernel AB: blocks 0..511 convert src/tgt f32 -> bf16 (src pre-scaled by log2e).
// Blocks 512..519: per-tgt top2/cls/conf -> colbias; full label histogram;
// per-class confident counts; zero S/ctrl/accs; per-class feature sums
// T[c][d] (live tgt rows) and U[c][d] (src rows by label) via pipelined
// register accumulation -> 8 partials each.
__global__ __launch_bounds__(256) void kAB(const float4* __restrict__ src4,
                                           const float4* __restrict__ tgt4,
                                           const int* __restrict__ labels,
                                           const float* __restrict__ logits,
                                           const float* __restrict__ tgtf,
                                           const float* __restrict__ srcf,
                                           ushort4* __restrict__ srcb,
                                           ushort4* __restrict__ tgtb,
                                           float* __restrict__ S,
                                           float* __restrict__ colbias,
                                           float* __restrict__ cc_part,
                                           float* __restrict__ counts_g,
                                           float* __restrict__ accs,
                                           int* __restrict__ ctrl,
                                           float* __restrict__ U_part,
                                           float* __restrict__ T_part) {
    __shared__ float hist[NC];
    __shared__ float chist[NC];
    __shared__ unsigned char clsl[1024];
    __shared__ float red[4 * 640];

    int t = threadIdx.x;
    int b = blockIdx.x;

    if (b < 512) {
        int tid = b * 256 + t;    // 131072 threads cover 8192*64/4 float4s
        float4 s = src4[tid];
        ushort4 os;
        os.x = f2bf_rne(s.x * LOG2E); os.y = f2bf_rne(s.y * LOG2E);
        os.z = f2bf_rne(s.z * LOG2E); os.w = f2bf_rne(s.w * LOG2E);
        srcb[tid] = os;
        float4 v = tgt4[tid];
        ushort4 ot;
        ot.x = f2bf_rne(v.x); ot.y = f2bf_rne(v.y);
        ot.z = f2bf_rne(v.z); ot.w = f2bf_rne(v.w);
        tgtb[tid] = ot;
        return;
    }

    int lb = b - 512;             // 0..7
    int base = lb * 1024;         // this block's 1024 tgt rows AND 1024 src rows

    if (t < NC) { hist[t] = 0.0f; chist[t] = 0.0f; }
    __syncthreads();

    // full label histogram (8192 labels, L2-hot)
    #pragma unroll
    for (int it = 0; it < 32; ++it) atomicAdd(&hist[labels[it * 256 + t]], 1.0f);

    // top-2 over 10 logits, 4 rows per thread
    int cls4[4]; int conf4[4];
    #pragma unroll
    for (int r = 0; r < 4; ++r) {
        int i = base + r * 256 + t;
        float m1 = -3.0e38f, m2 = -3.0e38f; int cls = 0;
        #pragma unroll
        for (int c = 0; c < NC; ++c) {
            float v = logits[i * NC + c];
            if (v > m1) { m2 = m1; m1 = v; cls = c; }
            else if (v > m2) { m2 = v; }
        }
        cls4[r] = cls;
        conf4[r] = (m1 - m2) >= 0.1f;
    }
    __syncthreads();   // hist complete

    #pragma unroll
    for (int r = 0; r < 4; ++r) {
        int i = base + r * 256 + t;
        float cnt = hist[cls4[r]];
        int live = conf4[r] && (cnt > 0.0f);
        colbias[i] = live ? (log2f(cnt) - SHIFT2) : NEG_BIG;
        S[i] = 0.0f;
        clsl[r * 256 + t] = live ? (unsigned char)cls4[r] : (unsigned char)255;
        if (conf4[r]) atomicAdd(&chist[cls4[r]], 1.0f);
    }
    __syncthreads();

    if (t < NC) cc_part[lb * NC + t] = chist[t];
    if (lb == 0) {
        if (t < NC) counts_g[t] = hist[t];
        if (t < 2) accs[t] = 0.0f;          // [0]=termL
        if (t < 129) ctrl[t] = 0;           // rowg_cnt[128] + final_cnt
    }

    int w = t >> 6, lane = t & 63;

    // ---- T accumulation (live tgt rows, class from clsl) ----
    float Ta[NC];
    #pragma unroll
    for (int c = 0; c < NC; ++c) Ta[c] = 0.0f;
    #pragma unroll
    for (int ch = 0; ch < 4; ++ch) {
        int rowb = base + w * 256 + ch * 64;
        int myc = (int)clsl[w * 256 + ch * 64 + lane];
        const float* rowp = tgtf + (size_t)rowb * DD + lane;
        float pA[8], pB[8];
        LD8(pA, 0) LD8(pB, 1)
        AC8(pA, 0, Ta) LD8(pA, 2)
        AC8(pB, 1, Ta) LD8(pB, 3)
        AC8(pA, 2, Ta) LD8(pA, 4)
        AC8(pB, 3, Ta) LD8(pB, 5)
        AC8(pA, 4, Ta) LD8(pA, 6)
        AC8(pB, 5, Ta) LD8(pB, 7)
        AC8(pA, 6, Ta)
        AC8(pB, 7, Ta)
    }
    #pragma unroll
    for (int c = 0; c < NC; ++c) red[w * 640 + c * 64 + lane] = Ta[c];
    __syncthreads();
    for (int idx = t; idx < 640; idx += 256)
        T_part[lb * 640 + idx] =
            red[idx] + red[640 + idx] + red[1280 + idx] + red[1920 + idx];
    __syncthreads();   // red reused below

    // ---- U accumulation (src rows by label) ----
    float Ua[NC];
    #pragma unroll
    for (int c = 0; c < NC; ++c) Ua[c] = 0.0f;
    #pragma unroll
    for (int ch = 0; ch < 4; ++ch) {
        int rowb = base + w * 256 + ch * 64;
        int myc = labels[rowb + lane];
        const float* rowp = srcf + (size_t)rowb * DD + lane;
        float pA[8], pB[8];
        LD8(pA, 0) LD8(pB, 1)
        AC8(pA, 0, Ua) LD8(pA, 2)
        AC8(pB, 1, Ua) LD8(pB, 3)
        AC8(pA, 2, Ua) LD8(pA, 4)
        AC8(pB, 3, Ua) LD8(pB, 5)
        AC8(pA, 4, Ua) LD8(pA, 6)
        AC8(pB, 5, Ua) LD8(pB, 7)
        AC8(pA, 6, Ua)
        AC8(pB, 7, Ua)
    }
    #pragma unroll
    for (int c = 0; c < NC; ++c) red[w * 640 + c * 64 + lane] = Ua[c];
    __syncthreads();
    for (int idx = t; idx < 640; idx += 256)
        U_part[lb * 640 + idx] =
            red[idx] + red[640 + idx] + red[1280 + idx] + red[1920 + idx];
}

// Kernel CD: fused bf16 MFMA GEMM + exp2 row-sum (triple-buffered 2-deep
// prefetch), per-rowgroup last-block termL finalize, overall last-block
// term1 (U.T dot, exact f32) + scalar finale.
//
// Coherence: cross-block data flows through device-scope atomic RMWs; read
// back with agent-scope atomic loads (bypass L1/L2). kAB outputs are coherent
// via the kernel-launch boundary. No __threadfence (agent fence = full L2
// writeback+invalidate per block; cost 245us in R2).
#define LOADT(bx0, bx1, cbx, ctv) {                                            \
    int cb_ = col0 + (ctv) * 16;                                               \
    const bf16x8* q_ = (const bf16x8*)(tgtb + (size_t)(cb_ + l15) * DD + quad * 8); \
    bx0 = q_[0]; bx1 = q_[4]; cbx = colbias[cb_ + l15]; }
#define COMPT(bx0, bx1, cbx) { _Pragma("unroll")                               \
    for (int mb = 0; mb < 4; ++mb) {                                           \
        f32x4 acc = {cbx, cbx, cbx, cbx};                                      \
        acc = MFMA16(a[mb][0], bx0, acc);                                      \
        acc = MFMA16(a[mb][1], bx1, acc);                                      \
        _Pragma("unroll")                                                      \
        for (int r = 0; r < 4; ++r) rs[mb][r] += EXP2(acc[r]); } }

__global__ __launch_bounds__(256) void kCD(const unsigned short* __restrict__ srcb,
                                           const unsigned short* __restrict__ tgtb,
                                           const float* __restrict__ colbias,
                                           const int* __restrict__ labels,
                                           const float* __restrict__ cc_part,
                                           const float* __restrict__ counts_g,
                                           const float* __restrict__ U_part,
                                           const float* __restrict__ T_part,
                                           float* __restrict__ S,
                                           float* __restrict__ accs,
                                           int* __restrict__ ctrl,
                                           float* __restrict__ out) {
    __shared__ float lds[4][64];
    __shared__ float t1red[4];
    __shared__ float ccl[NC];
    __shared__ int flag1, flag2;

    int t = threadIdx.x;
    int w = t >> 6;
    int lane = t & 63;
    int l15 = lane & 15;
    int quad = lane >> 4;
    int colchunk = blockIdx.x & 15;
    int rowg = blockIdx.x >> 4;
    int row_base = rowg * 64;

    bf16x8 a[4][2];
    #pragma unroll
    for (int mb = 0; mb < 4; ++mb) {
        const bf16x8* p = (const bf16x8*)(srcb + (size_t)(row_base + mb * 16 + l15) * DD + quad * 8);
        a[mb][0] = p[0];
        a[mb][1] = p[4];
    }

    float rs[4][4];
    #pragma unroll
    for (int mb = 0; mb < 4; ++mb)
        #pragma unroll
        for (int r = 0; r < 4; ++r) rs[mb][r] = 0.0f;

    int col0 = colchunk * 512 + w * 128;

    // fully-unrolled 8 tiles, named X/Y/Z buffers, loads issued 2 tiles early
    bf16x8 x0, x1, y0, y1, z0, z1;
    float cx, cy, cz;
    LOADT(x0, x1, cx, 0)
    LOADT(y0, y1, cy, 1)
    LOADT(z0, z1, cz, 2)  COMPT(x0, x1, cx)
    LOADT(x0, x1, cx, 3)  COMPT(y0, y1, cy)
    LOADT(y0, y1, cy, 4)  COMPT(z0, z1, cz)
    LOADT(z0, z1, cz, 5)  COMPT(x0, x1, cx)
    LOADT(x0, x1, cx, 6)  COMPT(y0, y1, cy)
    LOADT(y0, y1, cy, 7)  COMPT(z0, z1, cz)
    COMPT(x0, x1, cx)
    COMPT(y0, y1, cy)

    // row sums: reduce over 16 column-lanes per quad, cross-wave via LDS
    #pragma unroll
    for (int mb = 0; mb < 4; ++mb) {
        #pragma unroll
        for (int r = 0; r < 4; ++r) {
            float v = rs[mb][r];
            v += __shfl_xor(v, 1);
            v += __shfl_xor(v, 2);
            v += __shfl_xor(v, 4);
            v += __shfl_xor(v, 8);
            if (l15 == 0) lds[w][mb * 16 + quad * 4 + r] = v;
        }
    }
    __syncthreads();
    if (t < 64)
        atomicAdd(&S[row_base + t], lds[0][t] + lds[1][t] + lds[2][t] + lds[3][t]);

    // rowgroup finalize: 16th-done block computes termL for its 64 rows.
    __syncthreads();   // emits s_waitcnt vmcnt(0): S atomics complete
    if (t == 0) { int old = atomicAdd(&ctrl[rowg], 1); flag1 = (old == 15) ? 1 : 0; }
    __syncthreads();
    if (!flag1) return;

    if (t < NC) {
        float s = 0.0f;
        #pragma unroll
        for (int p = 0; p < 8; ++p) s += cc_part[p * NC + t];
        ccl[t] = s;
    }
    __syncthreads();
    float val = 0.0f;
    if (t < 64) {
        float s = __hip_atomic_load(&S[row_base + t], __ATOMIC_RELAXED, __HIP_MEMORY_SCOPE_AGENT);
        float L = (log2f(s) + SHIFT2) * LN2;
        val = ccl[labels[row_base + t]] * L;
    }
    if (w == 0) {
        #pragma unroll
        for (int m = 1; m < 64; m <<= 1) val += __shfl_xor(val, m);
        if (t == 0) atomicAdd(&accs[0], val);
    }
    if (t == 0) {
        asm volatile("s_waitcnt vmcnt(0)" ::: "memory");  // accs add complete before count bump
        int o2 = atomicAdd(&ctrl[128], 1);
        flag2 = (o2 == 127) ? 1 : 0;
    }
    __syncthreads();
    if (!flag2) return;

    // overall last block: term1 = sum_c U[c].T[c] (exact f32, natural units)
    float t1loc = 0.0f;
    #pragma unroll
    for (int g = 0; g < 3; ++g) {
        int idx = g * 256 + t;
        if (idx < 640) {
            float u = 0.0f, tv = 0.0f;
            #pragma unroll
            for (int p = 0; p < 8; ++p) {
                u  += U_part[p * 640 + idx];
                tv += T_part[p * 640 + idx];
            }
            t1loc += u * tv;
        }
    }
    #pragma unroll
    for (int m = 1; m < 64; m <<= 1) t1loc += __shfl_xor(t1loc, m);
    if (lane == 0) t1red[w] = t1loc;
    __syncthreads();
    if (t == 0) {
        float t1v = t1red[0] + t1red[1] + t1red[2] + t1red[3];
        float tl  = __hip_atomic_load(&accs[0], __ATOMIC_RELAXED, __HIP_MEMORY_SCOPE_AGENT);
        float P = 0.0f;
        #pragma unroll
        for (int c = 0; c < NC; ++c) P += counts_g[c] * ccl[c];
        out[0] = (t1v - tl) / (-(float)BSZ * P);
    }
}

extern "C" void kernel_launch(void* const* d_in, const int* in_sizes, int n_in,
                              void* d_out, int out_size, void* d_ws, size_t ws_size,
                              hipStream_t stream) {
    const float* src    = (const float*)d_in[0];
    const int*   labels = (const int*)d_in[1];
    const float* tgt    = (const float*)d_in[2];
    const float* logits = (const float*)d_in[3];

    char* ws = (char*)d_ws;
    float* S        = (float*)(ws + 0);        // 32768 B, zeroed by kAB
    float* colbias  = (float*)(ws + 32768);    // 32768 B
    float* cc_part  = (float*)(ws + 65536);    // 320 B
    float* counts_g = (float*)(ws + 65856);    // 40 B
    float* accs     = (float*)(ws + 65896);    // 8 B [termL]
    int*   ctrl     = (int*)(ws + 65920);      // 516 B [rowg_cnt[128], final_cnt]
    float* U_part   = (float*)(ws + 66560);    // 20480 B
    float* T_part   = (float*)(ws + 87040);    // 20480 B
    unsigned short* srcb = (unsigned short*)(ws + 131072);            // 1 MiB
    unsigned short* tgtb = (unsigned short*)(ws + 131072 + 1048576);  // 1 MiB

    kAB<<<520, 256, 0, stream>>>((const float4*)src, (const float4*)tgt, labels, logits,
                                 tgt, src, (ushort4*)srcb, (ushort4*)tgtb,
                                 S, colbias, cc_part, counts_g, accs, ctrl, U_part, T_part);
    kCD<<<2048, 256, 0, stream>>>(srcb, tgtb, colbias, labels,
                                  cc_part, counts_g, U_part, T_part,
                                  S, accs, ctrl, (float*)d_out);
}

// Round 5
// 166.540 us; speedup vs baseline: 1.1605x; 1.1605x over previous
//
#include <hip/hip_runtime.h>
#include <hip/hip_bf16.h>

#define BSZ 8192
#define BTZ 8192
#define DD 64
#define NC 10
#define SHIFT2 20.0f   // log2-domain shift
#define LN2 0.69314718055994531f
#define LOG2E 1.44269504088896341f
#define NEG_BIG -1.0e30f

typedef __attribute__((ext_vector_type(8))) short bf16x8;
typedef __attribute__((ext_vector_type(4))) float f32x4;

#if defined(__has_builtin)
#if __has_builtin(__builtin_amdgcn_exp2f)
#define EXP2(x) __builtin_amdgcn_exp2f(x)
#else
#define EXP2(x) exp2f(x)
#endif
#else
#define EXP2(x) exp2f(x)
#endif

#define MFMA16(A, B, C) __builtin_amdgcn_mfma_f32_16x16x32_bf16(A, B, C, 0, 0, 0)

__device__ __forceinline__ unsigned short f2bf_rne(float f) {
    unsigned int u = __float_as_uint(f);
    u += 0x7FFFu + ((u >> 16) & 1u);
    return (unsigned short)(u >> 16);
}

// Kernel AB: blocks 0..511 convert src/tgt f32 -> bf16 (src pre-scaled by log2e).
// Blocks 512..543 (32 tail blocks, 256 rows each): per-tgt top2/cls/conf ->
// colbias; full label histogram; per-class confident counts; zero S/ctrl/accs;
// per-class feature sums T[c][d] (conf tgt rows) and U[c][d] (src rows by
// label) via BRANCHLESS LDS float atomics (1 ds_add_f32 per row per lane;
// addresses stride-1 across lanes -> conflict-free). T over conf-only is safe:
// U[c]=0 for classes with no src rows, so U.T is unchanged.
__global__ __launch_bounds__(256) void kAB(const float4* __restrict__ src4,
                                           const float4* __restrict__ tgt4,
                                           const int* __restrict__ labels,
                                           const float* __restrict__ logits,
                                           const float* __restrict__ tgtf,
                                           const float* __restrict__ srcf,
                                           ushort4* __restrict__ srcb,
                                           ushort4* __restrict__ tgtb,
                                           float* __restrict__ S,
                                           float* __restrict__ colbias,
                                           float* __restrict__ cc_part,
                                           float* __restrict__ counts_g,
                                           float* __restrict__ accs,
                                           int* __restrict__ ctrl,
                                           float* __restrict__ U_part,
                                           float* __restrict__ T_part) {
    __shared__ float hist[NC];
    __shared__ float chist[NC];
    __shared__ float Tsh[640];
    __shared__ float Ush[640];
    __shared__ unsigned char clsl[256];
    __shared__ unsigned char labl[256];

    int t = threadIdx.x;
    int b = blockIdx.x;

    if (b < 512) {
        int tid = b * 256 + t;    // 131072 threads cover 8192*64/4 float4s
        float4 s = src4[tid];
        ushort4 os;
        os.x = f2bf_rne(s.x * LOG2E); os.y = f2bf_rne(s.y * LOG2E);
        os.z = f2bf_rne(s.z * LOG2E); os.w = f2bf_rne(s.w * LOG2E);
        srcb[tid] = os;
        float4 v = tgt4[tid];
        ushort4 ot;
        ot.x = f2bf_rne(v.x); ot.y = f2bf_rne(v.y);
        ot.z = f2bf_rne(v.z); ot.w = f2bf_rne(v.w);
        tgtb[tid] = ot;
        return;
    }

    int lb = b - 512;             // 0..31
    int base = lb * 256;          // this block's 256 tgt rows AND 256 src rows

    if (t < NC) { hist[t] = 0.0f; chist[t] = 0.0f; }
    for (int idx = t; idx < 640; idx += 256) { Tsh[idx] = 0.0f; Ush[idx] = 0.0f; }
    labl[t] = (unsigned char)labels[base + t];
    __syncthreads();

    // full label histogram (8192 labels, L2-hot)
    #pragma unroll
    for (int it = 0; it < 32; ++it) atomicAdd(&hist[labels[it * 256 + t]], 1.0f);

    // top-2 over 10 logits, 1 row per thread
    int i = base + t;
    float m1 = -3.0e38f, m2 = -3.0e38f; int cls = 0;
    #pragma unroll
    for (int c = 0; c < NC; ++c) {
        float v = logits[i * NC + c];
        if (v > m1) { m2 = m1; m1 = v; cls = c; }
        else if (v > m2) { m2 = v; }
    }
    bool conf = (m1 - m2) >= 0.1f;
    __syncthreads();   // hist complete

    float cnt = hist[cls];
    bool live = conf && (cnt > 0.0f);
    colbias[i] = live ? (log2f(cnt) - SHIFT2) : NEG_BIG;
    S[i] = 0.0f;
    clsl[t] = conf ? (unsigned char)cls : (unsigned char)255;
    if (conf) atomicAdd(&chist[cls], 1.0f);
    __syncthreads();

    if (t < NC) cc_part[lb * NC + t] = chist[t];
    if (lb == 0) {
        if (t < NC) counts_g[t] = hist[t];
        if (t < 2) accs[t] = 0.0f;          // [0]=termL
        if (t < 129) ctrl[t] = 0;           // rowg_cnt[128] + final_cnt
    }

    int w = t >> 6, lane = t & 63;
    int rowb = base + w * 64;
    const float* tp = tgtf + (size_t)rowb * DD + lane;
    const float* sp = srcf + (size_t)rowb * DD + lane;

    // T: conf tgt rows, class row-uniform; 1 ds_add_f32 per row per lane
    #pragma unroll 8
    for (int k = 0; k < 64; ++k) {
        int c = (int)clsl[w * 64 + k];
        float v = tp[(size_t)k * DD];
        if (c != 255) atomicAdd(&Tsh[c * 64 + lane], v);
    }
    // U: all src rows by label
    #pragma unroll 8
    for (int k = 0; k < 64; ++k) {
        int c = (int)labl[w * 64 + k];
        float v = sp[(size_t)k * DD];
        atomicAdd(&Ush[c * 64 + lane], v);
    }
    __syncthreads();
    for (int idx = t; idx < 640; idx += 256) {
        T_part[lb * 640 + idx] = Tsh[idx];
        U_part[lb * 640 + idx] = Ush[idx];
    }
}

// Kernel CD: fused bf16 MFMA GEMM + exp2 row-sum (triple-buffered 2-deep
// prefetch), per-rowgroup last-block termL finalize, overall last-block
// term1 (U.T dot, exact f32) + scalar finale.
//
// Coherence: cross-block data flows through device-scope atomic RMWs; read
// back with agent-scope atomic loads (bypass L1/L2). kAB outputs are coherent
// via the kernel-launch boundary. No __threadfence (agent fence = full L2
// writeback+invalidate per block; cost 245us in R2).
#define LOADT(bx0, bx1, cbx, ctv) {                                            \
    int cb_ = col0 + (ctv) * 16;                                               \
    const bf16x8* q_ = (const bf16x8*)(tgtb + (size_t)(cb_ + l15) * DD + quad * 8); \
    bx0 = q_[0]; bx1 = q_[4]; cbx = colbias[cb_ + l15]; }
#define COMPT(bx0, bx1, cbx) { _Pragma("unroll")                               \
    for (int mb = 0; mb < 4; ++mb) {                                           \
        f32x4 acc = {cbx, cbx, cbx, cbx};                                      \
        acc = MFMA16(a[mb][0], bx0, acc);                                      \
        acc = MFMA16(a[mb][1], bx1, acc);                                      \
        _Pragma("unroll")                                                      \
        for (int r = 0; r < 4; ++r) rs[mb][r] += EXP2(acc[r]); } }

__global__ __launch_bounds__(256) void kCD(const unsigned short* __restrict__ srcb,
                                           const unsigned short* __restrict__ tgtb,
                                           const float* __restrict__ colbias,
                                           const int* __restrict__ labels,
                                           const float* __restrict__ cc_part,
                                           const float* __restrict__ counts_g,
                                           const float* __restrict__ U_part,
                                           const float* __restrict__ T_part,
                                           float* __restrict__ S,
                                           float* __restrict__ accs,
                                           int* __restrict__ ctrl,
                                           float* __restrict__ out) {
    __shared__ float lds[4][64];
    __shared__ float t1red[4];
    __shared__ float ccl[NC];
    __shared__ int flag1, flag2;

    int t = threadIdx.x;
    int w = t >> 6;
    int lane = t & 63;
    int l15 = lane & 15;
    int quad = lane >> 4;
    int colchunk = blockIdx.x & 15;
    int rowg = blockIdx.x >> 4;
    int row_base = rowg * 64;

    bf16x8 a[4][2];
    #pragma unroll
    for (int mb = 0; mb < 4; ++mb) {
        const bf16x8* p = (const bf16x8*)(srcb + (size_t)(row_base + mb * 16 + l15) * DD + quad * 8);
        a[mb][0] = p[0];
        a[mb][1] = p[4];
    }

    float rs[4][4];
    #pragma unroll
    for (int mb = 0; mb < 4; ++mb)
        #pragma unroll
        for (int r = 0; r < 4; ++r) rs[mb][r] = 0.0f;

    int col0 = colchunk * 512 + w * 128;

    // fully-unrolled 8 tiles, named X/Y/Z buffers, loads issued 2 tiles early
    bf16x8 x0, x1, y0, y1, z0, z1;
    float cx, cy, cz;
    LOADT(x0, x1, cx, 0)
    LOADT(y0, y1, cy, 1)
    LOADT(z0, z1, cz, 2)  COMPT(x0, x1, cx)
    LOADT(x0, x1, cx, 3)  COMPT(y0, y1, cy)
    LOADT(y0, y1, cy, 4)  COMPT(z0, z1, cz)
    LOADT(z0, z1, cz, 5)  COMPT(x0, x1, cx)
    LOADT(x0, x1, cx, 6)  COMPT(y0, y1, cy)
    LOADT(y0, y1, cy, 7)  COMPT(z0, z1, cz)
    COMPT(x0, x1, cx)
    COMPT(y0, y1, cy)

    // row sums: reduce over 16 column-lanes per quad, cross-wave via LDS
    #pragma unroll
    for (int mb = 0; mb < 4; ++mb) {
        #pragma unroll
        for (int r = 0; r < 4; ++r) {
            float v = rs[mb][r];
            v += __shfl_xor(v, 1);
            v += __shfl_xor(v, 2);
            v += __shfl_xor(v, 4);
            v += __shfl_xor(v, 8);
            if (l15 == 0) lds[w][mb * 16 + quad * 4 + r] = v;
        }
    }
    __syncthreads();
    if (t < 64)
        atomicAdd(&S[row_base + t], lds[0][t] + lds[1][t] + lds[2][t] + lds[3][t]);

    // rowgroup finalize: 16th-done block computes termL for its 64 rows.
    __syncthreads();   // emits s_waitcnt vmcnt(0): S atomics complete
    if (t == 0) { int old = atomicAdd(&ctrl[rowg], 1); flag1 = (old == 15) ? 1 : 0; }
    __syncthreads();
    if (!flag1) return;

    if (t < NC) {
        float s = 0.0f;
        #pragma unroll
        for (int p = 0; p < 32; ++p) s += cc_part[p * NC + t];
        ccl[t] = s;
    }
    __syncthreads();
    float val = 0.0f;
    if (t < 64) {
        float s = __hip_atomic_load(&S[row_base + t], __ATOMIC_RELAXED, __HIP_MEMORY_SCOPE_AGENT);
        float L = (log2f(s) + SHIFT2) * LN2;
        val = ccl[labels[row_base + t]] * L;
    }
    if (w == 0) {
        #pragma unroll
        for (int m = 1; m < 64; m <<= 1) val += __shfl_xor(val, m);
        if (t == 0) atomicAdd(&accs[0], val);
    }
    if (t == 0) {
        asm volatile("s_waitcnt vmcnt(0)" ::: "memory");  // accs add complete before count bump
        int o2 = atomicAdd(&ctrl[128], 1);
        flag2 = (o2 == 127) ? 1 : 0;
    }
    __syncthreads();
    if (!flag2) return;

    // overall last block: term1 = sum_c U[c].T[c] (exact f32, natural units)
    float t1loc = 0.0f;
    #pragma unroll
    for (int g = 0; g < 3; ++g) {
        int idx = g * 256 + t;
        if (idx < 640) {
            float u = 0.0f, tv = 0.0f;
            #pragma unroll
            for (int p = 0; p < 32; ++p) {
                u  += U_part[p * 640 + idx];
                tv += T_part[p * 640 + idx];
            }
            t1loc += u * tv;
        }
    }
    #pragma unroll
    for (int m = 1; m < 64; m <<= 1) t1loc += __shfl_xor(t1loc, m);
    if (lane == 0) t1red[w] = t1loc;
    __syncthreads();
    if (t == 0) {
        float t1v = t1red[0] + t1red[1] + t1red[2] + t1red[3];
        float tl  = __hip_atomic_load(&accs[0], __ATOMIC_RELAXED, __HIP_MEMORY_SCOPE_AGENT);
        float P = 0.0f;
        #pragma unroll
        for (int c = 0; c < NC; ++c) P += counts_g[c] * ccl[c];
        out[0] = (t1v - tl) / (-(float)BSZ * P);
    }
}

extern "C" void kernel_launch(void* const* d_in, const int* in_sizes, int n_in,
                              void* d_out, int out_size, void* d_ws, size_t ws_size,
                              hipStream_t stream) {
    const float* src    = (const float*)d_in[0];
    const int*   labels = (const int*)d_in[1];
    const float* tgt    = (const float*)d_in[2];
    const float* logits = (const float*)d_in[3];

    char* ws = (char*)d_ws;
    float* S        = (float*)(ws + 0);        // 32768 B, zeroed by kAB
    float* colbias  = (float*)(ws + 32768);    // 32768 B
    float* cc_part  = (float*)(ws + 65536);    // 1280 B
    float* counts_g = (float*)(ws + 66816);    // 40 B
    float* accs     = (float*)(ws + 66856);    // 8 B [termL]
    int*   ctrl     = (int*)(ws + 66880);      // 516 B [rowg_cnt[128], final_cnt]
    float* U_part   = (float*)(ws + 67584);    // 81920 B
    float* T_part   = (float*)(ws + 149504);   // 81920 B
    unsigned short* srcb = (unsigned short*)(ws + 262144);            // 1 MiB
    unsigned short* tgtb = (unsigned short*)(ws + 262144 + 1048576);  // 1 MiB

    kAB<<<544, 256, 0, stream>>>((const float4*)src, (const float4*)tgt, labels, logits,
                                 tgt, src, (ushort4*)srcb, (ushort4*)tgtb,
                                 S, colbias, cc_part, counts_g, accs, ctrl, U_part, T_part);
    kCD<<<2048, 256, 0, stream>>>(srcb, tgtb, colbias, labels,
                                  cc_part, counts_g, U_part, T_part,
                                  S, accs, ctrl, (float*)d_out);
}

// Round 6
// 159.029 us; speedup vs baseline: 1.2153x; 1.0472x over previous
//
#include <hip/hip_runtime.h>
#include <hip/hip_bf16.h>

#define BSZ 8192
#define BTZ 8192
#define DD 64
#define NC 10
#define SHIFT2 20.0f   // log2-domain shift
#define LN2 0.69314718055994531f
#define LOG2E 1.44269504088896341f
#define NEG_BIG -1.0e30f

typedef __attribute__((ext_vector_type(8))) short bf16x8;
typedef __attribute__((ext_vector_type(4))) float f32x4;

#if defined(__has_builtin)
#if __has_builtin(__builtin_amdgcn_exp2f)
#define EXP2(x) __builtin_amdgcn_exp2f(x)
#else
#define EXP2(x) exp2f(x)
#endif
#else
#define EXP2(x) exp2f(x)
#endif

#define MFMA16(A, B, C) __builtin_amdgcn_mfma_f32_16x16x32_bf16(A, B, C, 0, 0, 0)

__device__ __forceinline__ unsigned short f2bf_rne(float f) {
    unsigned int u = __float_as_uint(f);
    u += 0x7FFFu + ((u >> 16) & 1u);
    return (unsigned short)(u >> 16);
}

// Kernel AB: blocks 0..511 convert src/tgt f32 -> bf16 (src pre-scaled by log2e).
// Blocks 512..543 (32 tail blocks, 256 rows each): per-tgt top2/cls/conf ->
// colbias; full label histogram; per-class confident counts; zero S/ctrl/accs;
// per-class feature sums T[c][d] (conf tgt rows) and U[c][d] (src rows by label).
// T/U use a BATCHED two-phase structure: 32 unconditional global loads into
// registers (compiler batches -> one latency round-trip), THEN 32 LDS float
// atomics (stride-1 per lane, conflict-free). R5's interleaved
// ds_read->load->ds_add serialized every load (~600cy x 256 = 62us).
__global__ __launch_bounds__(256) void kAB(const float4* __restrict__ src4,
                                           const float4* __restrict__ tgt4,
                                           const int* __restrict__ labels,
                                           const float* __restrict__ logits,
                                           const float* __restrict__ tgtf,
                                           const float* __restrict__ srcf,
                                           ushort4* __restrict__ srcb,
                                           ushort4* __restrict__ tgtb,
                                           float* __restrict__ S,
                                           float* __restrict__ colbias,
                                           float* __restrict__ cc_part,
                                           float* __restrict__ counts_g,
                                           float* __restrict__ accs,
                                           int* __restrict__ ctrl,
                                           float* __restrict__ U_part,
                                           float* __restrict__ T_part) {
    __shared__ float hist[NC];
    __shared__ float chist[NC];
    __shared__ float Tsh[640];
    __shared__ float Ush[640];
    __shared__ unsigned char clsl[256];
    __shared__ unsigned char labl[256];

    int t = threadIdx.x;
    int b = blockIdx.x;

    if (b < 512) {
        int tid = b * 256 + t;    // 131072 threads cover 8192*64/4 float4s
        float4 s = src4[tid];
        ushort4 os;
        os.x = f2bf_rne(s.x * LOG2E); os.y = f2bf_rne(s.y * LOG2E);
        os.z = f2bf_rne(s.z * LOG2E); os.w = f2bf_rne(s.w * LOG2E);
        srcb[tid] = os;
        float4 v = tgt4[tid];
        ushort4 ot;
        ot.x = f2bf_rne(v.x); ot.y = f2bf_rne(v.y);
        ot.z = f2bf_rne(v.z); ot.w = f2bf_rne(v.w);
        tgtb[tid] = ot;
        return;
    }

    int lb = b - 512;             // 0..31
    int base = lb * 256;          // this block's 256 tgt rows AND 256 src rows

    if (t < NC) { hist[t] = 0.0f; chist[t] = 0.0f; }
    for (int idx = t; idx < 640; idx += 256) { Tsh[idx] = 0.0f; Ush[idx] = 0.0f; }
    labl[t] = (unsigned char)labels[base + t];
    __syncthreads();

    // full label histogram (8192 labels, L2-hot)
    #pragma unroll
    for (int it = 0; it < 32; ++it) atomicAdd(&hist[labels[it * 256 + t]], 1.0f);

    // top-2 over 10 logits, 1 row per thread
    int i = base + t;
    float m1 = -3.0e38f, m2 = -3.0e38f; int cls = 0;
    #pragma unroll
    for (int c = 0; c < NC; ++c) {
        float v = logits[i * NC + c];
        if (v > m1) { m2 = m1; m1 = v; cls = c; }
        else if (v > m2) { m2 = v; }
    }
    bool conf = (m1 - m2) >= 0.1f;
    __syncthreads();   // hist complete

    float cnt = hist[cls];
    bool live = conf && (cnt > 0.0f);
    colbias[i] = live ? (log2f(cnt) - SHIFT2) : NEG_BIG;
    S[i] = 0.0f;
    clsl[t] = conf ? (unsigned char)cls : (unsigned char)255;
    if (conf) atomicAdd(&chist[cls], 1.0f);
    __syncthreads();

    if (t < NC) cc_part[lb * NC + t] = chist[t];
    if (lb == 0) {
        if (t < NC) counts_g[t] = hist[t];
        if (t < 2) accs[t] = 0.0f;          // [0]=termL, [1]=term1
        if (t < 129) ctrl[t] = 0;           // rowg_cnt[128] + final_cnt
    }

    int w = t >> 6, lane = t & 63;
    int rowb = base + w * 64;
    const float* tp = tgtf + (size_t)rowb * DD + lane;
    const float* sp = srcf + (size_t)rowb * DD + lane;

    // T: conf tgt rows. Phase 1: 32 batched loads. Phase 2: 32 LDS atomics.
    #pragma unroll
    for (int g = 0; g < 2; ++g) {
        float v[32];
        #pragma unroll
        for (int kk = 0; kk < 32; ++kk) v[kk] = tp[(size_t)(g * 32 + kk) * DD];
        #pragma unroll
        for (int kk = 0; kk < 32; ++kk) {
            int c = (int)clsl[w * 64 + g * 32 + kk];
            if (c != 255) atomicAdd(&Tsh[c * 64 + lane], v[kk]);
        }
    }
    // U: all src rows by label, same structure
    #pragma unroll
    for (int g = 0; g < 2; ++g) {
        float v[32];
        #pragma unroll
        for (int kk = 0; kk < 32; ++kk) v[kk] = sp[(size_t)(g * 32 + kk) * DD];
        #pragma unroll
        for (int kk = 0; kk < 32; ++kk) {
            int c = (int)labl[w * 64 + g * 32 + kk];
            atomicAdd(&Ush[c * 64 + lane], v[kk]);
        }
    }
    __syncthreads();
    for (int idx = t; idx < 640; idx += 256) {
        T_part[lb * 640 + idx] = Tsh[idx];
        U_part[lb * 640 + idx] = Ush[idx];
    }
}

// Kernel CD: fused bf16 MFMA GEMM + exp2 row-sum (4-deep named-buffer
// pipeline), per-rowgroup last-block finalize (wave0: termL for 64 rows;
// wave1: a 5-index slice of the U.T term1 dot), overall last block emits
// the scalar from two accumulators.
//
// Coherence: cross-block data flows through device-scope atomic RMWs; read
// back with agent-scope atomic loads (bypass L1/L2). kAB outputs are coherent
// via the kernel-launch boundary. No __threadfence (agent fence = full L2
// writeback+invalidate per block; cost 245us in R2). __syncthreads drains
// each wave's outstanding atomics (vmcnt) before the ctrl counter bumps.
#define LOADT(bx0, bx1, cbx, ctv) {                                            \
    int cb_ = col0 + (ctv) * 16;                                               \
    const bf16x8* q_ = (const bf16x8*)(tgtb + (size_t)(cb_ + l15) * DD + quad * 8); \
    bx0 = q_[0]; bx1 = q_[4]; cbx = colbias[cb_ + l15]; }
#define COMPT(bx0, bx1, cbx) { _Pragma("unroll")                               \
    for (int mb = 0; mb < 4; ++mb) {                                           \
        f32x4 acc = {cbx, cbx, cbx, cbx};                                      \
        acc = MFMA16(a[mb][0], bx0, acc);                                      \
        acc = MFMA16(a[mb][1], bx1, acc);                                      \
        _Pragma("unroll")                                                      \
        for (int r = 0; r < 4; ++r) rs[mb][r] += EXP2(acc[r]); } }

__global__ __launch_bounds__(256) void kCD(const unsigned short* __restrict__ srcb,
                                           const unsigned short* __restrict__ tgtb,
                                           const float* __restrict__ colbias,
                                           const int* __restrict__ labels,
                                           const float* __restrict__ cc_part,
                                           const float* __restrict__ counts_g,
                                           const float* __restrict__ U_part,
                                           const float* __restrict__ T_part,
                                           float* __restrict__ S,
                                           float* __restrict__ accs,
                                           int* __restrict__ ctrl,
                                           float* __restrict__ out) {
    __shared__ float lds[4][64];
    __shared__ float ccl[NC];
    __shared__ int flag1, flag2;

    int t = threadIdx.x;
    int w = t >> 6;
    int lane = t & 63;
    int l15 = lane & 15;
    int quad = lane >> 4;
    int colchunk = blockIdx.x & 15;
    int rowg = blockIdx.x >> 4;
    int row_base = rowg * 64;

    bf16x8 a[4][2];
    #pragma unroll
    for (int mb = 0; mb < 4; ++mb) {
        const bf16x8* p = (const bf16x8*)(srcb + (size_t)(row_base + mb * 16 + l15) * DD + quad * 8);
        a[mb][0] = p[0];
        a[mb][1] = p[4];
    }

    float rs[4][4];
    #pragma unroll
    for (int mb = 0; mb < 4; ++mb)
        #pragma unroll
        for (int r = 0; r < 4; ++r) rs[mb][r] = 0.0f;

    int col0 = colchunk * 512 + w * 128;

    // 4-deep pipeline: 4 named buffer sets, loads issued 4 tiles early
    bf16x8 p0a, p0b, p1a, p1b, p2a, p2b, p3a, p3b;
    float c0, c1, c2, c3;
    LOADT(p0a, p0b, c0, 0)
    LOADT(p1a, p1b, c1, 1)
    LOADT(p2a, p2b, c2, 2)
    LOADT(p3a, p3b, c3, 3)
    COMPT(p0a, p0b, c0)  LOADT(p0a, p0b, c0, 4)
    COMPT(p1a, p1b, c1)  LOADT(p1a, p1b, c1, 5)
    COMPT(p2a, p2b, c2)  LOADT(p2a, p2b, c2, 6)
    COMPT(p3a, p3b, c3)  LOADT(p3a, p3b, c3, 7)
    COMPT(p0a, p0b, c0)
    COMPT(p1a, p1b, c1)
    COMPT(p2a, p2b, c2)
    COMPT(p3a, p3b, c3)

    // row sums: reduce over 16 column-lanes per quad, cross-wave via LDS
    #pragma unroll
    for (int mb = 0; mb < 4; ++mb) {
        #pragma unroll
        for (int r = 0; r < 4; ++r) {
            float v = rs[mb][r];
            v += __shfl_xor(v, 1);
            v += __shfl_xor(v, 2);
            v += __shfl_xor(v, 4);
            v += __shfl_xor(v, 8);
            if (l15 == 0) lds[w][mb * 16 + quad * 4 + r] = v;
        }
    }
    __syncthreads();
    if (t < 64)
        atomicAdd(&S[row_base + t], lds[0][t] + lds[1][t] + lds[2][t] + lds[3][t]);

    // rowgroup finalize: 16th-done block handles this rowgroup's epilogue.
    __syncthreads();   // drains S atomics (s_waitcnt vmcnt(0) before s_barrier)
    if (t == 0) { int old = atomicAdd(&ctrl[rowg], 1); flag1 = (old == 15) ? 1 : 0; }
    __syncthreads();
    if (!flag1) return;

    if (t < NC) {
        float s = 0.0f;
        #pragma unroll
        for (int p = 0; p < 32; ++p) s += cc_part[p * NC + t];
        ccl[t] = s;
    }
    __syncthreads();

    // wave 0: termL for this rowgroup's 64 rows
    float val = 0.0f;
    if (t < 64) {
        float s = __hip_atomic_load(&S[row_base + t], __ATOMIC_RELAXED, __HIP_MEMORY_SCOPE_AGENT);
        float L = (log2f(s) + SHIFT2) * LN2;
        val = ccl[labels[row_base + t]] * L;
    }
    if (w == 0) {
        #pragma unroll
        for (int m = 1; m < 64; m <<= 1) val += __shfl_xor(val, m);
        if (t == 0) atomicAdd(&accs[0], val);
    }
    // wave 1: this rowgroup's 5-index slice of term1 = sum_c U[c].T[c]
    if (w == 1) {
        float dv = 0.0f;
        int sl = t - 64;                       // 0..63
        if (sl < 5) {
            int idx = rowg * 5 + sl;           // 128*5 = 640 exact
            float u = 0.0f, tv = 0.0f;
            #pragma unroll
            for (int p = 0; p < 32; ++p) {
                u  += U_part[p * 640 + idx];
                tv += T_part[p * 640 + idx];
            }
            dv = u * tv;
        }
        dv += __shfl_xor(dv, 1);
        dv += __shfl_xor(dv, 2);
        dv += __shfl_xor(dv, 4);
        if (sl == 0) atomicAdd(&accs[1], dv);
    }
    __syncthreads();   // drains both waves' accs atomics
    if (t == 0) { int o2 = atomicAdd(&ctrl[128], 1); flag2 = (o2 == 127) ? 1 : 0; }
    __syncthreads();
    if (!flag2) return;

    if (t == 0) {
        float tl  = __hip_atomic_load(&accs[0], __ATOMIC_RELAXED, __HIP_MEMORY_SCOPE_AGENT);
        float t1v = __hip_atomic_load(&accs[1], __ATOMIC_RELAXED, __HIP_MEMORY_SCOPE_AGENT);
        float P = 0.0f;
        #pragma unroll
        for (int c = 0; c < NC; ++c) P += counts_g[c] * ccl[c];
        out[0] = (t1v - tl) / (-(float)BSZ * P);
    }
}

extern "C" void kernel_launch(void* const* d_in, const int* in_sizes, int n_in,
                              void* d_out, int out_size, void* d_ws, size_t ws_size,
                              hipStream_t stream) {
    const float* src    = (const float*)d_in[0];
    const int*   labels = (const int*)d_in[1];
    const float* tgt    = (const float*)d_in[2];
    const float* logits = (const float*)d_in[3];

    char* ws = (char*)d_ws;
    float* S        = (float*)(ws + 0);        // 32768 B, zeroed by kAB
    float* colbias  = (float*)(ws + 32768);    // 32768 B
    float* cc_part  = (float*)(ws + 65536);    // 1280 B
    float* counts_g = (float*)(ws + 66816);    // 40 B
    float* accs     = (float*)(ws + 66856);    // 8 B [termL, term1]
    int*   ctrl     = (int*)(ws + 66880);      // 516 B [rowg_cnt[128], final_cnt]
    float* U_part   = (float*)(ws + 67584);    // 81920 B
    float* T_part   = (float*)(ws + 149504);   // 81920 B
    unsigned short* srcb = (unsigned short*)(ws + 262144);            // 1 MiB
    unsigned short* tgtb = (unsigned short*)(ws + 262144 + 1048576);  // 1 MiB

    kAB<<<544, 256, 0, stream>>>((const float4*)src, (const float4*)tgt, labels, logits,
                                 tgt, src, (ushort4*)srcb, (ushort4*)tgtb,
                                 S, colbias, cc_part, counts_g, accs, ctrl, U_part, T_part);
    kCD<<<2048, 256, 0, stream>>>(srcb, tgtb, colbias, labels,
                                  cc_part, counts_g, U_part, T_part,
                                  S, accs, ctrl, (float*)d_out);
}

// Round 7
// 140.488 us; speedup vs baseline: 1.3757x; 1.1320x over previous
//
#include <hip/hip_runtime.h>
#include <hip/hip_bf16.h>

#define BSZ 8192
#define BTZ 8192
#define DD 64
#define NC 10
#define SHIFT2 20.0f   // log2-domain shift
#define LN2 0.69314718055994531f
#define LOG2E 1.44269504088896341f
#define NEG_BIG -1.0e30f

typedef __attribute__((ext_vector_type(8))) short bf16x8;
typedef __attribute__((ext_vector_type(4))) float f32x4;

#if defined(__has_builtin)
#if __has_builtin(__builtin_amdgcn_exp2f)
#define EXP2(x) __builtin_amdgcn_exp2f(x)
#else
#define EXP2(x) exp2f(x)
#endif
#else
#define EXP2(x) exp2f(x)
#endif

#define MFMA16(A, B, C) __builtin_amdgcn_mfma_f32_16x16x32_bf16(A, B, C, 0, 0, 0)

__device__ __forceinline__ unsigned short f2bf_rne(float f) {
    unsigned int u = __float_as_uint(f);
    u += 0x7FFFu + ((u >> 16) & 1u);
    return (unsigned short)(u >> 16);
}

// Kernel AB (uniform 512 blocks, 16 rows each -- NO special tail blocks).
// Each block: converts its 16 src rows + 16 tgt rows f32->bf16 (values kept
// in registers!), computes cls/conf for its 16 tgt rows, histograms all 8192
// labels (8 batched int4 loads -> LDS atomics), accumulates its T/U
// contribution in LDS (T[c][d] = sum of conf tgt rows of cls c; U[c][d] =
// sum of src rows with label c), then flushes nonzero cells via global f32
// atomics. cc (conf count per class) also via global atomics (integer-valued
// floats: order-invariant, exact). colbias/S written for its own rows.
// R5/R6 lesson: interleaved data-dependent load->LDS-atomic chains serialize
// at one memory latency per element under in-order issue; here every global
// load's address is independent of loaded data, so loads batch.
__global__ __launch_bounds__(256) void kAB(const float4* __restrict__ src4,
                                           const float4* __restrict__ tgt4,
                                           const int* __restrict__ labels,
                                           const float* __restrict__ logits,
                                           ushort4* __restrict__ srcb,
                                           ushort4* __restrict__ tgtb,
                                           float* __restrict__ S,
                                           float* __restrict__ colbias,
                                           float* __restrict__ cc_g,
                                           float* __restrict__ counts_g,
                                           float* __restrict__ T_g,
                                           float* __restrict__ U_g) {
    __shared__ float hist[NC];
    __shared__ float chist[NC];
    __shared__ float Tsh[640];
    __shared__ float Ush[640];
    __shared__ unsigned char clsl[16];   // 255 if !conf
    __shared__ unsigned char labl[16];

    int t = threadIdx.x;
    int b = blockIdx.x;
    int f = b * 256 + t;          // float4 index; rows b*16 .. b*16+15

    // issue main data loads first (independent addresses -> deep in flight)
    float4 s = src4[f];
    float4 v = tgt4[f];

    // batched label loads: 8 independent int4 loads (addresses data-independent)
    const int4* lab4 = (const int4*)labels;
    int4 lv[8];
    #pragma unroll
    for (int j = 0; j < 8; ++j) lv[j] = lab4[t * 8 + j];

    if (t < NC) { hist[t] = 0.0f; chist[t] = 0.0f; }
    for (int idx = t; idx < 640; idx += 256) { Tsh[idx] = 0.0f; Ush[idx] = 0.0f; }
    if (t < 16) labl[t] = (unsigned char)labels[b * 16 + t];
    __syncthreads();   // LDS zeroed

    // convert + store bf16 (overlaps with everything below)
    ushort4 os;
    os.x = f2bf_rne(s.x * LOG2E); os.y = f2bf_rne(s.y * LOG2E);
    os.z = f2bf_rne(s.z * LOG2E); os.w = f2bf_rne(s.w * LOG2E);
    srcb[f] = os;
    ushort4 ot;
    ot.x = f2bf_rne(v.x); ot.y = f2bf_rne(v.y);
    ot.z = f2bf_rne(v.z); ot.w = f2bf_rne(v.w);
    tgtb[f] = ot;

    // full label histogram from registers
    #pragma unroll
    for (int j = 0; j < 8; ++j) {
        atomicAdd(&hist[lv[j].x], 1.0f);
        atomicAdd(&hist[lv[j].y], 1.0f);
        atomicAdd(&hist[lv[j].z], 1.0f);
        atomicAdd(&hist[lv[j].w], 1.0f);
    }

    // top-2 over 10 logits for this block's 16 tgt rows
    if (t < 16) {
        int i = b * 16 + t;
        float m1 = -3.0e38f, m2 = -3.0e38f; int cls = 0;
        #pragma unroll
        for (int c = 0; c < NC; ++c) {
            float lg = logits[i * NC + c];
            if (lg > m1) { m2 = m1; m1 = lg; cls = c; }
            else if (lg > m2) { m2 = lg; }
        }
        clsl[t] = ((m1 - m2) >= 0.1f) ? (unsigned char)cls : (unsigned char)255;
    }
    __syncthreads();   // hist + clsl complete

    // colbias + S zero for this block's 16 tgt rows; chist (conf per class)
    if (t < 16) {
        int i = b * 16 + t;
        int c = (int)clsl[t];
        bool conf = (c != 255);
        float cnt = conf ? hist[c] : 0.0f;
        bool live = conf && (cnt > 0.0f);
        colbias[i] = live ? (log2f(cnt) - SHIFT2) : NEG_BIG;
        S[i] = 0.0f;
        if (conf) atomicAdd(&chist[c], 1.0f);
    }

    // T/U LDS accumulation: row r = t>>4, quarter q = t&15 (4 dims each)
    {
        int r = t >> 4, q = t & 15;
        int c = (int)clsl[r];
        if (c != 255) {
            atomicAdd(&Tsh[c * 64 + q * 4 + 0], v.x);
            atomicAdd(&Tsh[c * 64 + q * 4 + 1], v.y);
            atomicAdd(&Tsh[c * 64 + q * 4 + 2], v.z);
            atomicAdd(&Tsh[c * 64 + q * 4 + 3], v.w);
        }
        int cu = (int)labl[r];
        atomicAdd(&Ush[cu * 64 + q * 4 + 0], s.x);
        atomicAdd(&Ush[cu * 64 + q * 4 + 1], s.y);
        atomicAdd(&Ush[cu * 64 + q * 4 + 2], s.z);
        atomicAdd(&Ush[cu * 64 + q * 4 + 3], s.w);
    }
    __syncthreads();

    // flush block partials to global accumulators (skip zeros)
    for (int idx = t; idx < 640; idx += 256) {
        float tv = Tsh[idx];
        float uv = Ush[idx];
        if (tv != 0.0f) atomicAdd(&T_g[idx], tv);
        if (uv != 0.0f) atomicAdd(&U_g[idx], uv);
    }
    if (t < NC) atomicAdd(&cc_g[t], chist[t]);
    if (b == 0 && t < NC) counts_g[t] = hist[t];
}

// Kernel CD: fused bf16 MFMA GEMM + exp2 row-sum (4-deep named-buffer
// pipeline), per-rowgroup last-block finalize (wave0: termL for 64 rows;
// wave1: a 5-index slice of the U.T term1 dot), overall last block emits
// the scalar from two accumulators.
//
// Coherence: within-kernel cross-block data flows through device-scope
// atomic RMWs; read back with agent-scope atomic loads (bypass L1/L2).
// kAB outputs (incl. atomic-summed T_g/U_g/cc_g) are coherent via the
// kernel-launch boundary -> plain loads. No __threadfence (agent fence =
// full L2 writeback+invalidate per block; cost 245us in R2). __syncthreads
// drains each wave's outstanding atomics (vmcnt) before the ctrl bumps.
#define LOADT(bx0, bx1, cbx, ctv) {                                            \
    int cb_ = col0 + (ctv) * 16;                                               \
    const bf16x8* q_ = (const bf16x8*)(tgtb + (size_t)(cb_ + l15) * DD + quad * 8); \
    bx0 = q_[0]; bx1 = q_[4]; cbx = colbias[cb_ + l15]; }
#define COMPT(bx0, bx1, cbx) { _Pragma("unroll")                               \
    for (int mb = 0; mb < 4; ++mb) {                                           \
        f32x4 acc = {cbx, cbx, cbx, cbx};                                      \
        acc = MFMA16(a[mb][0], bx0, acc);                                      \
        acc = MFMA16(a[mb][1], bx1, acc);                                      \
        _Pragma("unroll")                                                      \
        for (int r = 0; r < 4; ++r) rs[mb][r] += EXP2(acc[r]); } }

__global__ __launch_bounds__(256) void kCD(const unsigned short* __restrict__ srcb,
                                           const unsigned short* __restrict__ tgtb,
                                           const float* __restrict__ colbias,
                                           const int* __restrict__ labels,
                                           const float* __restrict__ cc_g,
                                           const float* __restrict__ counts_g,
                                           const float* __restrict__ U_g,
                                           const float* __restrict__ T_g,
                                           float* __restrict__ S,
                                           float* __restrict__ accs,
                                           int* __restrict__ ctrl,
                                           float* __restrict__ out) {
    __shared__ float lds[4][64];
    __shared__ float ccl[NC];
    __shared__ int flag1, flag2;

    int t = threadIdx.x;
    int w = t >> 6;
    int lane = t & 63;
    int l15 = lane & 15;
    int quad = lane >> 4;
    int colchunk = blockIdx.x & 15;
    int rowg = blockIdx.x >> 4;
    int row_base = rowg * 64;

    bf16x8 a[4][2];
    #pragma unroll
    for (int mb = 0; mb < 4; ++mb) {
        const bf16x8* p = (const bf16x8*)(srcb + (size_t)(row_base + mb * 16 + l15) * DD + quad * 8);
        a[mb][0] = p[0];
        a[mb][1] = p[4];
    }

    float rs[4][4];
    #pragma unroll
    for (int mb = 0; mb < 4; ++mb)
        #pragma unroll
        for (int r = 0; r < 4; ++r) rs[mb][r] = 0.0f;

    int col0 = colchunk * 512 + w * 128;

    // 4-deep pipeline: 4 named buffer sets, loads issued 4 tiles early
    bf16x8 p0a, p0b, p1a, p1b, p2a, p2b, p3a, p3b;
    float c0, c1, c2, c3;
    LOADT(p0a, p0b, c0, 0)
    LOADT(p1a, p1b, c1, 1)
    LOADT(p2a, p2b, c2, 2)
    LOADT(p3a, p3b, c3, 3)
    COMPT(p0a, p0b, c0)  LOADT(p0a, p0b, c0, 4)
    COMPT(p1a, p1b, c1)  LOADT(p1a, p1b, c1, 5)
    COMPT(p2a, p2b, c2)  LOADT(p2a, p2b, c2, 6)
    COMPT(p3a, p3b, c3)  LOADT(p3a, p3b, c3, 7)
    COMPT(p0a, p0b, c0)
    COMPT(p1a, p1b, c1)
    COMPT(p2a, p2b, c2)
    COMPT(p3a, p3b, c3)

    // row sums: reduce over 16 column-lanes per quad, cross-wave via LDS
    #pragma unroll
    for (int mb = 0; mb < 4; ++mb) {
        #pragma unroll
        for (int r = 0; r < 4; ++r) {
            float v = rs[mb][r];
            v += __shfl_xor(v, 1);
            v += __shfl_xor(v, 2);
            v += __shfl_xor(v, 4);
            v += __shfl_xor(v, 8);
            if (l15 == 0) lds[w][mb * 16 + quad * 4 + r] = v;
        }
    }
    __syncthreads();
    if (t < 64)
        atomicAdd(&S[row_base + t], lds[0][t] + lds[1][t] + lds[2][t] + lds[3][t]);

    // rowgroup finalize: 16th-done block handles this rowgroup's epilogue.
    __syncthreads();   // drains S atomics (s_waitcnt vmcnt(0) before s_barrier)
    if (t == 0) { int old = atomicAdd(&ctrl[rowg], 1); flag1 = (old == 15) ? 1 : 0; }
    __syncthreads();
    if (!flag1) return;

    if (t < NC) ccl[t] = cc_g[t];
    __syncthreads();

    // wave 0: termL for this rowgroup's 64 rows
    float val = 0.0f;
    if (t < 64) {
        float s = __hip_atomic_load(&S[row_base + t], __ATOMIC_RELAXED, __HIP_MEMORY_SCOPE_AGENT);
        float L = (log2f(s) + SHIFT2) * LN2;
        val = ccl[labels[row_base + t]] * L;
    }
    if (w == 0) {
        #pragma unroll
        for (int m = 1; m < 64; m <<= 1) val += __shfl_xor(val, m);
        if (t == 0) atomicAdd(&accs[0], val);
    }
    // wave 1: this rowgroup's 5-index slice of term1 = sum_c U[c].T[c]
    if (w == 1) {
        float dv = 0.0f;
        int sl = t - 64;                       // 0..63
        if (sl < 5) {
            int idx = rowg * 5 + sl;           // 128*5 = 640 exact
            dv = U_g[idx] * T_g[idx];
        }
        dv += __shfl_xor(dv, 1);
        dv += __shfl_xor(dv, 2);
        dv += __shfl_xor(dv, 4);
        if (sl == 0) atomicAdd(&accs[1], dv);
    }
    __syncthreads();   // drains both waves' accs atomics
    if (t == 0) { int o2 = atomicAdd(&ctrl[128], 1); flag2 = (o2 == 127) ? 1 : 0; }
    __syncthreads();
    if (!flag2) return;

    if (t == 0) {
        float tl  = __hip_atomic_load(&accs[0], __ATOMIC_RELAXED, __HIP_MEMORY_SCOPE_AGENT);
        float t1v = __hip_atomic_load(&accs[1], __ATOMIC_RELAXED, __HIP_MEMORY_SCOPE_AGENT);
        float P = 0.0f;
        #pragma unroll
        for (int c = 0; c < NC; ++c) P += counts_g[c] * ccl[c];
        out[0] = (t1v - tl) / (-(float)BSZ * P);
    }
}

extern "C" void kernel_launch(void* const* d_in, const int* in_sizes, int n_in,
                              void* d_out, int out_size, void* d_ws, size_t ws_size,
                              hipStream_t stream) {
    const float* src    = (const float*)d_in[0];
    const int*   labels = (const int*)d_in[1];
    const float* tgt    = (const float*)d_in[2];
    const float* logits = (const float*)d_in[3];

    char* ws = (char*)d_ws;
    float* S        = (float*)(ws + 0);        // 32768 B, zeroed by kAB
    float* colbias  = (float*)(ws + 32768);    // 32768 B, written by kAB
    // ---- memset region [65536, 71680): global atomic accumulators + ctrl ----
    float* cc_g     = (float*)(ws + 65536);    // 40 B
    float* accs     = (float*)(ws + 65600);    // 8 B [termL, term1]
    int*   ctrl     = (int*)(ws + 65664);      // 516 B [rowg_cnt[128], final_cnt]
    float* T_g      = (float*)(ws + 66560);    // 2560 B
    float* U_g      = (float*)(ws + 69120);    // 2560 B
    // -------------------------------------------------------------------------
    float* counts_g = (float*)(ws + 73728);    // 40 B, written by block 0
    unsigned short* srcb = (unsigned short*)(ws + 131072);            // 1 MiB
    unsigned short* tgtb = (unsigned short*)(ws + 131072 + 1048576);  // 1 MiB

    hipMemsetAsync(ws + 65536, 0, 6144, stream);
    kAB<<<512, 256, 0, stream>>>((const float4*)src, (const float4*)tgt, labels, logits,
                                 (ushort4*)srcb, (ushort4*)tgtb,
                                 S, colbias, cc_g, counts_g, T_g, U_g);
    kCD<<<2048, 256, 0, stream>>>(srcb, tgtb, colbias, labels,
                                  cc_g, counts_g, U_g, T_g,
                                  S, accs, ctrl, (float*)d_out);
}

// Round 8
// 126.318 us; speedup vs baseline: 1.5300x; 1.1122x over previous
//
#include <hip/hip_runtime.h>
#include <hip/hip_bf16.h>

#define BSZ 8192
#define BTZ 8192
#define DD 64
#define NC 10
#define SHIFT2 20.0f   // log2-domain shift
#define LN2 0.69314718055994531f
#define LOG2E 1.44269504088896341f
#define NEG_BIG -1.0e30f

typedef __attribute__((ext_vector_type(8))) short bf16x8;
typedef __attribute__((ext_vector_type(4))) float f32x4;

#if defined(__has_builtin)
#if __has_builtin(__builtin_amdgcn_exp2f)
#define EXP2(x) __builtin_amdgcn_exp2f(x)
#else
#define EXP2(x) exp2f(x)
#endif
#else
#define EXP2(x) exp2f(x)
#endif

#define MFMA16(A, B, C) __builtin_amdgcn_mfma_f32_16x16x32_bf16(A, B, C, 0, 0, 0)

__device__ __forceinline__ unsigned short f2bf_rne(float f) {
    unsigned int u = __float_as_uint(f);
    u += 0x7FFFu + ((u >> 16) & 1u);
    return (unsigned short)(u >> 16);
}

// Kernel AB (uniform 512 blocks, 16 rows each).
// Each block: converts its 16 src+16 tgt rows f32->bf16 (register-resident),
// computes cls/conf for its 16 tgt rows, histograms all 8192 labels via
// per-thread PACKED u64 counters (two u64s, five 12-bit fields each;
// per-thread max 32/class fits, wave-64 sum max 2048 fits) + 64-lane
// butterfly -- ZERO same-address atomic storms (R7's 8192 LDS atomics/block
// were ~800-deep serial RMW chains). T/U accumulated in LDS (shallow chains:
// 16 rows), then flushed to 8-WAY global partials (chain depth 64, not 512).
__global__ __launch_bounds__(256) void kAB(const float4* __restrict__ src4,
                                           const float4* __restrict__ tgt4,
                                           const int* __restrict__ labels,
                                           const float* __restrict__ logits,
                                           ushort4* __restrict__ srcb,
                                           ushort4* __restrict__ tgtb,
                                           float* __restrict__ S,
                                           float* __restrict__ colbias,
                                           float* __restrict__ cc_part8,
                                           float* __restrict__ counts_g,
                                           float* __restrict__ T_part8,
                                           float* __restrict__ U_part8) {
    __shared__ float hist[NC];
    __shared__ float hpart[4][NC];
    __shared__ float chist[16];
    __shared__ float Tsh[640];
    __shared__ float Ush[640];
    __shared__ unsigned char clsl[16];   // 255 if !conf
    __shared__ unsigned char labl[16];

    int t = threadIdx.x;
    int b = blockIdx.x;
    int f = b * 256 + t;          // float4 index; rows b*16 .. b*16+15

    // issue main data loads first (independent addresses -> deep in flight)
    float4 s = src4[f];
    float4 v = tgt4[f];

    // batched label loads: 8 independent int4 loads
    const int4* lab4 = (const int4*)labels;
    int4 lv[8];
    #pragma unroll
    for (int j = 0; j < 8; ++j) lv[j] = lab4[t * 8 + j];

    if (t < 16) { chist[t] = 0.0f; labl[t] = (unsigned char)labels[b * 16 + t]; }
    for (int idx = t; idx < 640; idx += 256) { Tsh[idx] = 0.0f; Ush[idx] = 0.0f; }

    // convert + store bf16
    ushort4 os;
    os.x = f2bf_rne(s.x * LOG2E); os.y = f2bf_rne(s.y * LOG2E);
    os.z = f2bf_rne(s.z * LOG2E); os.w = f2bf_rne(s.w * LOG2E);
    srcb[f] = os;
    ushort4 ot;
    ot.x = f2bf_rne(v.x); ot.y = f2bf_rne(v.y);
    ot.z = f2bf_rne(v.z); ot.w = f2bf_rne(v.w);
    tgtb[f] = ot;

    // packed-u64 histogram: classes 0..4 in A (12-bit fields), 5..9 in B
    unsigned long long A = 0ULL, B = 0ULL;
    #pragma unroll
    for (int j = 0; j < 8; ++j) {
        int cs[4] = { lv[j].x, lv[j].y, lv[j].z, lv[j].w };
        #pragma unroll
        for (int e = 0; e < 4; ++e) {
            int c = cs[e];
            bool lo = (c < 5);
            int sh = 12 * (lo ? c : c - 5);
            unsigned long long one = 1ULL << sh;
            A += lo ? one : 0ULL;
            B += lo ? 0ULL : one;
        }
    }
    #pragma unroll
    for (int m = 1; m < 64; m <<= 1) {
        A += __shfl_xor(A, m);
        B += __shfl_xor(B, m);
    }
    int w = t >> 6, lane = t & 63;
    if (lane < NC) {
        float cnt = (lane < 5) ? (float)((A >> (12 * lane)) & 0xFFFULL)
                               : (float)((B >> (12 * (lane - 5))) & 0xFFFULL);
        hpart[w][lane] = cnt;
    }

    // top-2 over 10 logits for this block's 16 tgt rows
    if (t < 16) {
        int i = b * 16 + t;
        float m1 = -3.0e38f, m2 = -3.0e38f; int cls = 0;
        #pragma unroll
        for (int c = 0; c < NC; ++c) {
            float lg = logits[i * NC + c];
            if (lg > m1) { m2 = m1; m1 = lg; cls = c; }
            else if (lg > m2) { m2 = lg; }
        }
        clsl[t] = ((m1 - m2) >= 0.1f) ? (unsigned char)cls : (unsigned char)255;
    }
    __syncthreads();   // hpart, clsl, labl, chist, Tsh/Ush-zero visible
    if (t < NC) hist[t] = hpart[0][t] + hpart[1][t] + hpart[2][t] + hpart[3][t];
    __syncthreads();   // hist visible

    // colbias + S zero for this block's 16 tgt rows; chist (conf per class)
    if (t < 16) {
        int i = b * 16 + t;
        int c = (int)clsl[t];
        bool conf = (c != 255);
        float cnt = conf ? hist[c] : 0.0f;
        bool live = conf && (cnt > 0.0f);
        colbias[i] = live ? (log2f(cnt) - SHIFT2) : NEG_BIG;
        S[i] = 0.0f;
        if (conf) atomicAdd(&chist[c], 1.0f);
    }

    // T/U LDS accumulation: row r = t>>4, quarter q = t&15 (4 dims each)
    {
        int r = t >> 4, q = t & 15;
        int c = (int)clsl[r];
        if (c != 255) {
            atomicAdd(&Tsh[c * 64 + q * 4 + 0], v.x);
            atomicAdd(&Tsh[c * 64 + q * 4 + 1], v.y);
            atomicAdd(&Tsh[c * 64 + q * 4 + 2], v.z);
            atomicAdd(&Tsh[c * 64 + q * 4 + 3], v.w);
        }
        int cu = (int)labl[r];
        atomicAdd(&Ush[cu * 64 + q * 4 + 0], s.x);
        atomicAdd(&Ush[cu * 64 + q * 4 + 1], s.y);
        atomicAdd(&Ush[cu * 64 + q * 4 + 2], s.z);
        atomicAdd(&Ush[cu * 64 + q * 4 + 3], s.w);
    }
    __syncthreads();

    // flush block partials to 8-way global partial accumulators
    int slot = b & 7;
    for (int idx = t; idx < 640; idx += 256) {
        float tv = Tsh[idx];
        float uv = Ush[idx];
        if (tv != 0.0f) atomicAdd(&T_part8[slot * 640 + idx], tv);
        if (uv != 0.0f) atomicAdd(&U_part8[slot * 640 + idx], uv);
    }
    if (t < NC) atomicAdd(&cc_part8[slot * 16 + t], chist[t]);
    if (b == 0 && t < NC) counts_g[t] = hist[t];
}

// Kernel CD: fused bf16 MFMA GEMM + exp2 row-sum. BM=128 (mb=8 per wave):
// halves the dominant redundant B-column traffic vs BM=64 (R7: 128 MB of
// L2/L3 re-reads with capped MLP was the ~49us stall; all pipes <10%).
// Grid 1024 = 64 rowgroups x 16 colchunks. Per-rowgroup 16th-done block
// finalizes: waves 0-1 termL for 128 rows; wave 2 the rowgroup's 10-index
// slice of term1 = sum_c U[c].T[c]. 64th finalizer emits the scalar.
//
// Coherence: cross-block data via device-scope atomic RMWs, read back with
// agent-scope atomic loads. kAB outputs coherent via kernel boundary. No
// __threadfence (agent fence = L2 writeback+invalidate; cost 245us in R2).
#define LOADT(bx0, bx1, cbx, ctv) {                                            \
    int cb_ = col0 + (ctv) * 16;                                               \
    const bf16x8* q_ = (const bf16x8*)(tgtb + (size_t)(cb_ + l15) * DD + quad * 8); \
    bx0 = q_[0]; bx1 = q_[4]; cbx = colbias[cb_ + l15]; }
#define COMPT(bx0, bx1, cbx) { _Pragma("unroll")                               \
    for (int mb = 0; mb < 8; ++mb) {                                           \
        f32x4 acc = {cbx, cbx, cbx, cbx};                                      \
        acc = MFMA16(a[mb][0], bx0, acc);                                      \
        acc = MFMA16(a[mb][1], bx1, acc);                                      \
        _Pragma("unroll")                                                      \
        for (int r = 0; r < 4; ++r) rs[mb][r] += EXP2(acc[r]); } }

__global__ __launch_bounds__(256) void kCD(const unsigned short* __restrict__ srcb,
                                           const unsigned short* __restrict__ tgtb,
                                           const float* __restrict__ colbias,
                                           const int* __restrict__ labels,
                                           const float* __restrict__ cc_part8,
                                           const float* __restrict__ counts_g,
                                           const float* __restrict__ U_part8,
                                           const float* __restrict__ T_part8,
                                           float* __restrict__ S,
                                           float* __restrict__ accs,
                                           int* __restrict__ ctrl,
                                           float* __restrict__ out) {
    __shared__ float lds[4][128];
    __shared__ float ccl[NC];
    __shared__ int flag1, flag2;

    int t = threadIdx.x;
    int w = t >> 6;
    int lane = t & 63;
    int l15 = lane & 15;
    int quad = lane >> 4;
    int colchunk = blockIdx.x & 15;
    int rowg = blockIdx.x >> 4;      // 0..63
    int row_base = rowg * 128;

    bf16x8 a[8][2];
    #pragma unroll
    for (int mb = 0; mb < 8; ++mb) {
        const bf16x8* p = (const bf16x8*)(srcb + (size_t)(row_base + mb * 16 + l15) * DD + quad * 8);
        a[mb][0] = p[0];
        a[mb][1] = p[4];
    }

    float rs[8][4];
    #pragma unroll
    for (int mb = 0; mb < 8; ++mb)
        #pragma unroll
        for (int r = 0; r < 4; ++r) rs[mb][r] = 0.0f;

    int col0 = colchunk * 512 + w * 128;

    // 4-deep pipeline: 4 named buffer sets, loads issued 4 tiles early
    bf16x8 p0a, p0b, p1a, p1b, p2a, p2b, p3a, p3b;
    float c0, c1, c2, c3;
    LOADT(p0a, p0b, c0, 0)
    LOADT(p1a, p1b, c1, 1)
    LOADT(p2a, p2b, c2, 2)
    LOADT(p3a, p3b, c3, 3)
    COMPT(p0a, p0b, c0)  LOADT(p0a, p0b, c0, 4)
    COMPT(p1a, p1b, c1)  LOADT(p1a, p1b, c1, 5)
    COMPT(p2a, p2b, c2)  LOADT(p2a, p2b, c2, 6)
    COMPT(p3a, p3b, c3)  LOADT(p3a, p3b, c3, 7)
    COMPT(p0a, p0b, c0)
    COMPT(p1a, p1b, c1)
    COMPT(p2a, p2b, c2)
    COMPT(p3a, p3b, c3)

    // row sums: reduce over 16 column-lanes per quad, cross-wave via LDS
    #pragma unroll
    for (int mb = 0; mb < 8; ++mb) {
        #pragma unroll
        for (int r = 0; r < 4; ++r) {
            float v = rs[mb][r];
            v += __shfl_xor(v, 1);
            v += __shfl_xor(v, 2);
            v += __shfl_xor(v, 4);
            v += __shfl_xor(v, 8);
            if (l15 == 0) lds[w][mb * 16 + quad * 4 + r] = v;
        }
    }
    __syncthreads();
    if (t < 128)
        atomicAdd(&S[row_base + t], lds[0][t] + lds[1][t] + lds[2][t] + lds[3][t]);

    // rowgroup finalize: 16th-done block handles this rowgroup's epilogue.
    __syncthreads();   // drains S atomics (s_waitcnt vmcnt(0) before s_barrier)
    if (t == 0) { int old = atomicAdd(&ctrl[rowg], 1); flag1 = (old == 15) ? 1 : 0; }
    __syncthreads();
    if (!flag1) return;

    if (t < NC) {
        float s = 0.0f;
        #pragma unroll
        for (int p = 0; p < 8; ++p) s += cc_part8[p * 16 + t];
        ccl[t] = s;
    }
    __syncthreads();

    // waves 0-1: termL for this rowgroup's 128 rows
    float val = 0.0f;
    if (t < 128) {
        float s = __hip_atomic_load(&S[row_base + t], __ATOMIC_RELAXED, __HIP_MEMORY_SCOPE_AGENT);
        float L = (log2f(s) + SHIFT2) * LN2;
        val = ccl[labels[row_base + t]] * L;
    }
    if (w < 2) {
        #pragma unroll
        for (int m = 1; m < 64; m <<= 1) val += __shfl_xor(val, m);
        if (lane == 0) atomicAdd(&accs[0], val);
    }
    // wave 2: this rowgroup's 10-index slice of term1 = sum_c U[c].T[c]
    if (w == 2) {
        float dv = 0.0f;
        int sl = t - 128;                      // 0..63
        if (sl < 10) {
            int idx = rowg * 10 + sl;          // 64*10 = 640 exact
            float u = 0.0f, tv = 0.0f;
            #pragma unroll
            for (int p = 0; p < 8; ++p) {
                u  += U_part8[p * 640 + idx];
                tv += T_part8[p * 640 + idx];
            }
            dv = u * tv;
        }
        dv += __shfl_xor(dv, 1);
        dv += __shfl_xor(dv, 2);
        dv += __shfl_xor(dv, 4);
        dv += __shfl_xor(dv, 8);
        if (sl == 0) atomicAdd(&accs[1], dv);
    }
    __syncthreads();   // drains all waves' accs atomics
    if (t == 0) { int o2 = atomicAdd(&ctrl[64], 1); flag2 = (o2 == 63) ? 1 : 0; }
    __syncthreads();
    if (!flag2) return;

    if (t == 0) {
        float tl  = __hip_atomic_load(&accs[0], __ATOMIC_RELAXED, __HIP_MEMORY_SCOPE_AGENT);
        float t1v = __hip_atomic_load(&accs[1], __ATOMIC_RELAXED, __HIP_MEMORY_SCOPE_AGENT);
        float P = 0.0f;
        #pragma unroll
        for (int c = 0; c < NC; ++c) P += counts_g[c] * ccl[c];
        out[0] = (t1v - tl) / (-(float)BSZ * P);
    }
}

extern "C" void kernel_launch(void* const* d_in, const int* in_sizes, int n_in,
                              void* d_out, int out_size, void* d_ws, size_t ws_size,
                              hipStream_t stream) {
    const float* src    = (const float*)d_in[0];
    const int*   labels = (const int*)d_in[1];
    const float* tgt    = (const float*)d_in[2];
    const float* logits = (const float*)d_in[3];

    char* ws = (char*)d_ws;
    float* S        = (float*)(ws + 0);        // 32768 B, zeroed by kAB
    float* colbias  = (float*)(ws + 32768);    // 32768 B, written by kAB
    // ---- memset region [65536, 108544): global atomic accumulators + ctrl ----
    float* cc_part8 = (float*)(ws + 65536);    // 512 B (8 slots x 16)
    float* accs     = (float*)(ws + 66048);    // 8 B [termL, term1]
    int*   ctrl     = (int*)(ws + 66112);      // 260 B [rowg_cnt[64], final_cnt@64]
    float* T_part8  = (float*)(ws + 67584);    // 20480 B
    float* U_part8  = (float*)(ws + 88064);    // 20480 B
    // --------------------------------------------------------------------------
    float* counts_g = (float*)(ws + 110592);   // 40 B, written by block 0
    unsigned short* srcb = (unsigned short*)(ws + 131072);            // 1 MiB
    unsigned short* tgtb = (unsigned short*)(ws + 131072 + 1048576);  // 1 MiB

    hipMemsetAsync(ws + 65536, 0, 43008, stream);
    kAB<<<512, 256, 0, stream>>>((const float4*)src, (const float4*)tgt, labels, logits,
                                 (ushort4*)srcb, (ushort4*)tgtb,
                                 S, colbias, cc_part8, counts_g, T_part8, U_part8);
    kCD<<<1024, 256, 0, stream>>>(srcb, tgtb, colbias, labels,
                                  cc_part8, counts_g, U_part8, T_part8,
                                  S, accs, ctrl, (float*)d_out);
}